// Round 4
// baseline (491.277 us; speedup 1.0000x reference)
//
#include <hip/hip_runtime.h>
#include <hip/hip_bf16.h>
#include <math.h>

#define NN 100000
#define NE 3200000
#define NPAD 100096
#define NB 196        // buckets: dst>>9, 512 nodes each
#define BN 512        // nodes per bucket
#define EPB 4096      // edges per block in hist/scatter passes
#define NBLK 782      // ceil(NE/EPB)

typedef __attribute__((ext_vector_type(8))) short short8;
typedef __attribute__((ext_vector_type(4))) float floatx4;
typedef __attribute__((ext_vector_type(4))) unsigned uint4v;

// ---------------- bf16 helpers (storage bf16, math fp32) ----------------
__device__ __forceinline__ unsigned short bf16_of(float x) {
    __hip_bfloat16 h = __float2bfloat16(x);  // RNE
    return *(unsigned short*)&h;
}
__device__ __forceinline__ unsigned pack2(float a, float b) {
    return (unsigned)bf16_of(a) | ((unsigned)bf16_of(b) << 16);
}
__device__ __forceinline__ float lo_f(unsigned u) { return __uint_as_float(u << 16); }
__device__ __forceinline__ float hi_f(unsigned u) { return __uint_as_float(u & 0xffff0000u); }
__device__ __forceinline__ void acc8(float* a, uint4v r) {
    a[0] += lo_f(r[0]); a[1] += hi_f(r[0]);
    a[2] += lo_f(r[1]); a[3] += hi_f(r[1]);
    a[4] += lo_f(r[2]); a[5] += hi_f(r[2]);
    a[6] += lo_f(r[3]); a[7] += hi_f(r[3]);
}
__device__ __forceinline__ float dot8(uint4v a, uint4v b) {
    return lo_f(a[0]) * lo_f(b[0]) + hi_f(a[0]) * hi_f(b[0])
         + lo_f(a[1]) * lo_f(b[1]) + hi_f(a[1]) * hi_f(b[1])
         + lo_f(a[2]) * lo_f(b[2]) + hi_f(a[2]) * hi_f(b[2])
         + lo_f(a[3]) * lo_f(b[3]) + hi_f(a[3]) * hi_f(b[3]);
}

// ---------------- pass A: per-block bucket histogram (bucket-major out) ----------------
__global__ __launch_bounds__(256) void hist_kernel(const int* __restrict__ dst,
                                                   int* __restrict__ blkhist) {
    __shared__ int cnt[NB];
    int t = threadIdx.x;
    for (int i = t; i < NB; i += 256) cnt[i] = 0;
    __syncthreads();
    int e0 = blockIdx.x * EPB;
    int e1 = min(e0 + EPB, NE);
    for (int e = e0 + t; e < e1; e += 256) atomicAdd(&cnt[dst[e] >> 9], 1);
    __syncthreads();
    for (int i = t; i < NB; i += 256) blkhist[i * NBLK + blockIdx.x] = cnt[i];
}

// ---------------- pass B1: per-bucket exclusive scan along blocks ----------------
__global__ __launch_bounds__(64) void scanA_kernel(int* __restrict__ blkhist,
                                                   int* __restrict__ totals) {
    int j = blockIdx.x, lane = threadIdx.x;
    int base = j * NBLK;
    int carry = 0;
    for (int c = 0; c < NBLK; c += 64) {
        int b = c + lane;
        int v = (b < NBLK) ? blkhist[base + b] : 0;
        int inc = v;
#pragma unroll
        for (int m = 1; m < 64; m <<= 1) {
            int u = __shfl_up(inc, m, 64);
            if (lane >= m) inc += u;
        }
        if (b < NBLK) blkhist[base + b] = carry + inc - v;
        carry += __shfl(inc, 63, 64);
    }
    if (lane == 0) totals[j] = carry;
}

// ---------------- pass B2: bucket bases ----------------
__global__ __launch_bounds__(256) void scanB_kernel(const int* __restrict__ totals,
                                                    int* __restrict__ bucket_base) {
    __shared__ int sm[NB];
    int t = threadIdx.x;
    if (t < NB) sm[t] = totals[t];
    __syncthreads();
    if (t == 0) {
        int r = 0;
        for (int i = 0; i < NB; ++i) { bucket_base[i] = r; r += sm[i]; }
        bucket_base[NB] = r;
    }
}

// ---------------- pass C: LDS-staged scatter -> contiguous run writes ----------------
// Now also carries the original edge id (for CSR-ordered decode).
__global__ __launch_bounds__(256) void scatter_kernel(const int* __restrict__ src,
                                                      const int* __restrict__ dst,
                                                      const int* __restrict__ blkhist,
                                                      const int* __restrict__ bucket_base,
                                                      int2* __restrict__ staged) {
    __shared__ int cnt[NB];
    __shared__ int lbase[NB + 1];
    __shared__ int gbase[NB];
    __shared__ int sbufs[EPB];            // 16KB: (src<<9)|dlow
    __shared__ int sbufe[EPB];            // 16KB: original edge id
    __shared__ unsigned char sbkt[EPB];   // 4KB: bucket id per slot
    int t = threadIdx.x;
    for (int i = t; i < NB; i += 256) cnt[i] = 0;
    __syncthreads();
    int e0 = blockIdx.x * EPB;
    int e1 = min(e0 + EPB, NE);
    int cn = e1 - e0;
    for (int e = e0 + t; e < e1; e += 256) atomicAdd(&cnt[dst[e] >> 9], 1);
    __syncthreads();
    if (t < 64) {  // exclusive scan of 196 counts, 4 per lane
        int v[4]; int s = 0;
#pragma unroll
        for (int k = 0; k < 4; ++k) { int idx = t * 4 + k; v[k] = (idx < NB) ? cnt[idx] : 0; s += v[k]; }
        int inc = s;
#pragma unroll
        for (int m = 1; m < 64; m <<= 1) {
            int u = __shfl_up(inc, m, 64);
            if (t >= m) inc += u;
        }
        int run = inc - s;
#pragma unroll
        for (int k = 0; k < 4; ++k) { int idx = t * 4 + k; if (idx < NB) lbase[idx] = run; run += v[k]; }
        if (t == 63) lbase[NB] = inc;  // == cn
    }
    __syncthreads();
    for (int i = t; i < NB; i += 256) {
        gbase[i] = bucket_base[i] + blkhist[i * NBLK + blockIdx.x];
        cnt[i] = lbase[i];            // rank cursors
    }
    __syncthreads();
    for (int e = e0 + t; e < e1; e += 256) {
        int s = src[e], d = dst[e];
        int bk = d >> 9;
        int r = atomicAdd(&cnt[bk], 1);     // LDS atomic
        sbufs[r] = (s << 9) | (d & (BN - 1));
        sbufe[r] = e;
        sbkt[r] = (unsigned char)bk;
    }
    __syncthreads();
    for (int i = t; i < cn; i += 256) {     // contiguous run write-out
        int bk = sbkt[i];
        staged[gbase[bk] + i - lbase[bk]] = make_int2(sbufs[i], sbufe[i]);
    }
}

// ---------------- pass D: per-bucket fine counting sort + offsets + dis ----------------
__global__ __launch_bounds__(256) void fine_kernel(const int2* __restrict__ staged,
                                                   const int* __restrict__ bucket_base,
                                                   int* __restrict__ offset,
                                                   float* __restrict__ dis,
                                                   int* __restrict__ csr_src,
                                                   int* __restrict__ csr_eid) {
    __shared__ int hist[BN];
    __shared__ int offs[BN];
    __shared__ int cur[BN];
    int t = threadIdx.x, j = blockIdx.x;
    int bb = bucket_base[j], be = bucket_base[j + 1];
    for (int i = t; i < BN; i += 256) hist[i] = 0;
    __syncthreads();
    for (int e = bb + t; e < be; e += 256) atomicAdd(&hist[staged[e].x & (BN - 1)], 1);
    __syncthreads();
    if (t < 64) {  // wave0: exclusive scan of 512 counts
        int v[8]; int s = 0;
#pragma unroll
        for (int k = 0; k < 8; ++k) { v[k] = hist[t * 8 + k]; s += v[k]; }
        int inc = s;
#pragma unroll
        for (int m = 1; m < 64; m <<= 1) {
            int u = __shfl_up(inc, m, 64);
            if (t >= m) inc += u;
        }
        int run = inc - s;
#pragma unroll
        for (int k = 0; k < 8; ++k) { offs[t * 8 + k] = run; run += v[k]; }
    }
    __syncthreads();
    for (int l = t; l < BN; l += 256) {
        cur[l] = offs[l];
        int n = j * BN + l;
        if (n < NN) {
            offset[n] = bb + offs[l];
            dis[n] = rsqrtf((float)hist[l] + 1.0f);
        }
    }
    if (j == NB - 1 && t == 0) offset[NN] = NE;
    __syncthreads();
    for (int e = bb + t; e < be; e += 256) {
        int2 p = staged[e];
        int r = atomicAdd(&cur[p.x & (BN - 1)], 1);  // LDS atomic
        csr_src[bb + r] = p.x >> 9;
        csr_eid[bb + r] = p.y;
    }
}

// ---------------- matmul 1 (MFMA): ys1 = bf16(dis * (x @ W1)) ----------------
__global__ __launch_bounds__(256) void mm1_kernel(const float* __restrict__ x,
                                                  const float* __restrict__ W,
                                                  const float* __restrict__ dis,
                                                  unsigned short* __restrict__ y) {
    __shared__ unsigned short Wt[64][136];  // W^T bf16: [n][k], pad 8 shorts
    int t = threadIdx.x;
    for (int i = t; i < 128 * 64; i += 256) {
        int k = i >> 6, n = i & 63;
        Wt[n][k] = bf16_of(W[i]);
    }
    __syncthreads();
    int wave = t >> 6, lane = t & 63;
    int quad = lane >> 4, n16 = lane & 15;
    short8 bfr[4][4];  // [kstep][coltile]
#pragma unroll
    for (int s = 0; s < 4; ++s)
#pragma unroll
        for (int tt = 0; tt < 4; ++tt)
            bfr[s][tt] = *(const short8*)&Wt[tt * 16 + n16][s * 32 + quad * 8];
    int tile0 = (blockIdx.x * 4 + wave) * 4;
#pragma unroll 1
    for (int it = 0; it < 4; ++it) {
        int tile = tile0 + it;
        if (tile >= 6250) break;
        int m0 = tile * 16;
        const float* xp = x + (size_t)(m0 + n16) * 128 + quad * 8;
        floatx4 acc0 = {0,0,0,0}, acc1 = {0,0,0,0}, acc2 = {0,0,0,0}, acc3 = {0,0,0,0};
#pragma unroll
        for (int s = 0; s < 4; ++s) {
            floatx4 lo = __builtin_nontemporal_load((const floatx4*)(xp + s * 32));
            floatx4 hi = __builtin_nontemporal_load((const floatx4*)(xp + s * 32 + 4));
            short8 a;
            a[0] = (short)bf16_of(lo[0]); a[1] = (short)bf16_of(lo[1]);
            a[2] = (short)bf16_of(lo[2]); a[3] = (short)bf16_of(lo[3]);
            a[4] = (short)bf16_of(hi[0]); a[5] = (short)bf16_of(hi[1]);
            a[6] = (short)bf16_of(hi[2]); a[7] = (short)bf16_of(hi[3]);
            acc0 = __builtin_amdgcn_mfma_f32_16x16x32_bf16(a, bfr[s][0], acc0, 0, 0, 0);
            acc1 = __builtin_amdgcn_mfma_f32_16x16x32_bf16(a, bfr[s][1], acc1, 0, 0, 0);
            acc2 = __builtin_amdgcn_mfma_f32_16x16x32_bf16(a, bfr[s][2], acc2, 0, 0, 0);
            acc3 = __builtin_amdgcn_mfma_f32_16x16x32_bf16(a, bfr[s][3], acc3, 0, 0, 0);
        }
#pragma unroll
        for (int r = 0; r < 4; ++r) {
            int ro = m0 + quad * 4 + r;
            float sc = dis[ro];
            unsigned short* yp = y + (size_t)ro * 64 + n16;
            yp[0]  = bf16_of(acc0[r] * sc);
            yp[16] = bf16_of(acc1[r] * sc);
            yp[32] = bf16_of(acc2[r] * sc);
            yp[48] = bf16_of(acc3[r] * sc);
        }
    }
}

// ---------------- matmul 2 (MFMA): ys2 = bf16(dis * (h @ W2)), h bf16 ----------------
__global__ __launch_bounds__(256) void mm2_kernel(const unsigned short* __restrict__ h,
                                                  const float* __restrict__ W,
                                                  const float* __restrict__ dis,
                                                  unsigned short* __restrict__ y) {
    __shared__ unsigned short Wt[32][72];  // W^T bf16: [n][k], pad 8
    int t = threadIdx.x;
    for (int i = t; i < 64 * 32; i += 256) {
        int k = i >> 5, n = i & 31;
        Wt[n][k] = bf16_of(W[i]);
    }
    __syncthreads();
    int wave = t >> 6, lane = t & 63;
    int quad = lane >> 4, n16 = lane & 15;
    short8 bfr[2][2];
#pragma unroll
    for (int s = 0; s < 2; ++s)
#pragma unroll
        for (int tt = 0; tt < 2; ++tt)
            bfr[s][tt] = *(const short8*)&Wt[tt * 16 + n16][s * 32 + quad * 8];
    int tile0 = (blockIdx.x * 4 + wave) * 4;
#pragma unroll 1
    for (int it = 0; it < 4; ++it) {
        int tile = tile0 + it;
        if (tile >= 6250) break;
        int m0 = tile * 16;
        const unsigned short* hp = h + (size_t)(m0 + n16) * 64 + quad * 8;
        floatx4 acc0 = {0,0,0,0}, acc1 = {0,0,0,0};
#pragma unroll
        for (int s = 0; s < 2; ++s) {
            short8 a = *(const short8*)(hp + s * 32);
            acc0 = __builtin_amdgcn_mfma_f32_16x16x32_bf16(a, bfr[s][0], acc0, 0, 0, 0);
            acc1 = __builtin_amdgcn_mfma_f32_16x16x32_bf16(a, bfr[s][1], acc1, 0, 0, 0);
        }
#pragma unroll
        for (int r = 0; r < 4; ++r) {
            int ro = m0 + quad * 4 + r;
            float sc = dis[ro];
            unsigned short* yp = y + (size_t)ro * 32 + n16;
            yp[0]  = bf16_of(acc0[r] * sc);
            yp[16] = bf16_of(acc1[r] * sc);
        }
    }
}

// ---------------- fused gather-aggregate, dim 64 bf16 -> h bf16 ----------------
__global__ __launch_bounds__(256) void agg64_kernel(const uint4v* __restrict__ ys4,
                                                    const float* __restrict__ dis,
                                                    const int* __restrict__ offset,
                                                    const int* __restrict__ csr_src,
                                                    const float* __restrict__ b,
                                                    uint4v* __restrict__ h4) {
    int tid = blockIdx.x * 256 + threadIdx.x;
    int nd = tid >> 3, c = tid & 7;
    if (nd >= NN) return;
    int start = offset[nd], end = offset[nd + 1];
    float acc[8] = {0, 0, 0, 0, 0, 0, 0, 0};
    acc8(acc, ys4[(size_t)nd * 8 + c]);  // self-loop term
    if (start < end) {
        int last = end - 1;
        int sk[8];
#pragma unroll
        for (int k = 0; k < 8; ++k) sk[k] = csr_src[min(start + k, last)];
        for (int i = start; i < end; i += 8) {
            uint4v r0 = ys4[(size_t)sk[0] * 8 + c];
            uint4v r1 = ys4[(size_t)sk[1] * 8 + c];
            uint4v r2 = ys4[(size_t)sk[2] * 8 + c];
            uint4v r3 = ys4[(size_t)sk[3] * 8 + c];
            uint4v r4 = ys4[(size_t)sk[4] * 8 + c];
            uint4v r5 = ys4[(size_t)sk[5] * 8 + c];
            uint4v r6 = ys4[(size_t)sk[6] * 8 + c];
            uint4v r7 = ys4[(size_t)sk[7] * 8 + c];
            int i2 = i + 8;
            if (i2 < end) {
#pragma unroll
                for (int k = 0; k < 8; ++k) sk[k] = csr_src[min(i2 + k, last)];
            }
            int rem = end - i;  // >= 1
            acc8(acc, r0);
            if (rem > 1) acc8(acc, r1);
            if (rem > 2) acc8(acc, r2);
            if (rem > 3) acc8(acc, r3);
            if (rem > 4) acc8(acc, r4);
            if (rem > 5) acc8(acc, r5);
            if (rem > 6) acc8(acc, r6);
            if (rem > 7) acc8(acc, r7);
        }
    }
    float ds = dis[nd];
    const float4 bv0 = *(const float4*)&b[c * 8];
    const float4 bv1 = *(const float4*)&b[c * 8 + 4];
    uint4v o;
    o[0] = pack2(fmaxf(fmaf(ds, acc[0], bv0.x), 0.f), fmaxf(fmaf(ds, acc[1], bv0.y), 0.f));
    o[1] = pack2(fmaxf(fmaf(ds, acc[2], bv0.z), 0.f), fmaxf(fmaf(ds, acc[3], bv0.w), 0.f));
    o[2] = pack2(fmaxf(fmaf(ds, acc[4], bv1.x), 0.f), fmaxf(fmaf(ds, acc[5], bv1.y), 0.f));
    o[3] = pack2(fmaxf(fmaf(ds, acc[6], bv1.z), 0.f), fmaxf(fmaf(ds, acc[7], bv1.w), 0.f));
    h4[(size_t)nd * 8 + c] = o;   // normal store: keep h resident in L2 for mm2
}

// ---------------- fused gather-aggregate, dim 32 bf16 -> z bf16 ----------------
__global__ __launch_bounds__(256) void agg32_kernel(const uint4v* __restrict__ ys4,
                                                    const float* __restrict__ dis,
                                                    const int* __restrict__ offset,
                                                    const int* __restrict__ csr_src,
                                                    const float* __restrict__ b,
                                                    uint4v* __restrict__ z4) {
    int tid = blockIdx.x * 256 + threadIdx.x;
    int nd = tid >> 2, c = tid & 3;
    if (nd >= NN) return;
    int start = offset[nd], end = offset[nd + 1];
    float acc[8] = {0, 0, 0, 0, 0, 0, 0, 0};
    acc8(acc, ys4[(size_t)nd * 4 + c]);
    if (start < end) {
        int last = end - 1;
        int sk[8];
#pragma unroll
        for (int k = 0; k < 8; ++k) sk[k] = csr_src[min(start + k, last)];
        for (int i = start; i < end; i += 8) {
            uint4v r0 = ys4[(size_t)sk[0] * 4 + c];
            uint4v r1 = ys4[(size_t)sk[1] * 4 + c];
            uint4v r2 = ys4[(size_t)sk[2] * 4 + c];
            uint4v r3 = ys4[(size_t)sk[3] * 4 + c];
            uint4v r4 = ys4[(size_t)sk[4] * 4 + c];
            uint4v r5 = ys4[(size_t)sk[5] * 4 + c];
            uint4v r6 = ys4[(size_t)sk[6] * 4 + c];
            uint4v r7 = ys4[(size_t)sk[7] * 4 + c];
            int i2 = i + 8;
            if (i2 < end) {
#pragma unroll
                for (int k = 0; k < 8; ++k) sk[k] = csr_src[min(i2 + k, last)];
            }
            int rem = end - i;
            acc8(acc, r0);
            if (rem > 1) acc8(acc, r1);
            if (rem > 2) acc8(acc, r2);
            if (rem > 3) acc8(acc, r3);
            if (rem > 4) acc8(acc, r4);
            if (rem > 5) acc8(acc, r5);
            if (rem > 6) acc8(acc, r6);
            if (rem > 7) acc8(acc, r7);
        }
    }
    float ds = dis[nd];
    const float4 bv0 = *(const float4*)&b[c * 8];
    const float4 bv1 = *(const float4*)&b[c * 8 + 4];
    uint4v o;
    o[0] = pack2(fmaf(ds, acc[0], bv0.x), fmaf(ds, acc[1], bv0.y));
    o[1] = pack2(fmaf(ds, acc[2], bv0.z), fmaf(ds, acc[3], bv0.w));
    o[2] = pack2(fmaf(ds, acc[4], bv1.x), fmaf(ds, acc[5], bv1.y));
    o[3] = pack2(fmaf(ds, acc[6], bv1.z), fmaf(ds, acc[7], bv1.w));
    z4[(size_t)nd * 4 + c] = o;   // normal store: keep z resident in L2 for decode
}

// ---------------- decode (CSR order): one 4-lane group per dst node ----------------
// z[dst] lives in registers; only z[src] is gathered (halves random line touches).
// Results scattered to out[eid]; out stays L2-resident so 4B writes merge.
__global__ __launch_bounds__(256) void decode_csr_kernel(const uint4v* __restrict__ z4,
                                                         const int* __restrict__ offset,
                                                         const int* __restrict__ csr_src,
                                                         const int* __restrict__ csr_eid,
                                                         float* __restrict__ out) {
    int tid = blockIdx.x * 256 + threadIdx.x;
    int nd = tid >> 2, k = tid & 3;
    if (nd >= NN) return;
    int start = offset[nd], end = offset[nd + 1];
    if (start >= end) return;
    uint4v zd = z4[(size_t)nd * 4 + k];   // this node's 16B slice of its z row
    int last = end - 1;
    int sk[8], ek[8];
#pragma unroll
    for (int q = 0; q < 8; ++q) sk[q] = csr_src[min(start + q, last)];
#pragma unroll
    for (int q = 0; q < 8; ++q) ek[q] = csr_eid[min(start + q, last)];
    for (int i = start; i < end; i += 8) {
        uint4v r0 = z4[(size_t)sk[0] * 4 + k];
        uint4v r1 = z4[(size_t)sk[1] * 4 + k];
        uint4v r2 = z4[(size_t)sk[2] * 4 + k];
        uint4v r3 = z4[(size_t)sk[3] * 4 + k];
        uint4v r4 = z4[(size_t)sk[4] * 4 + k];
        uint4v r5 = z4[(size_t)sk[5] * 4 + k];
        uint4v r6 = z4[(size_t)sk[6] * 4 + k];
        uint4v r7 = z4[(size_t)sk[7] * 4 + k];
        int ec0 = ek[0], ec1 = ek[1], ec2 = ek[2], ec3 = ek[3];
        int ec4 = ek[4], ec5 = ek[5], ec6 = ek[6], ec7 = ek[7];
        int i2 = i + 8;
        if (i2 < end) {
#pragma unroll
            for (int q = 0; q < 8; ++q) sk[q] = csr_src[min(i2 + q, last)];
#pragma unroll
            for (int q = 0; q < 8; ++q) ek[q] = csr_eid[min(i2 + q, last)];
        }
        // per-lane partial dots, then reduce across the 4-lane group
        float d0 = dot8(zd, r0), d1 = dot8(zd, r1), d2 = dot8(zd, r2), d3 = dot8(zd, r3);
        float d4 = dot8(zd, r4), d5 = dot8(zd, r5), d6 = dot8(zd, r6), d7 = dot8(zd, r7);
#pragma unroll
        for (int m = 2; m >= 1; m >>= 1) {
            d0 += __shfl_xor(d0, m, 4); d1 += __shfl_xor(d1, m, 4);
            d2 += __shfl_xor(d2, m, 4); d3 += __shfl_xor(d3, m, 4);
            d4 += __shfl_xor(d4, m, 4); d5 += __shfl_xor(d5, m, 4);
            d6 += __shfl_xor(d6, m, 4); d7 += __shfl_xor(d7, m, 4);
        }
        // lane k stores edges q=k and q=k+4
        float va = (k & 2) ? ((k & 1) ? d3 : d2) : ((k & 1) ? d1 : d0);
        float vb = (k & 2) ? ((k & 1) ? d7 : d6) : ((k & 1) ? d5 : d4);
        int ea = (k & 2) ? ((k & 1) ? ec3 : ec2) : ((k & 1) ? ec1 : ec0);
        int eb = (k & 2) ? ((k & 1) ? ec7 : ec6) : ((k & 1) ? ec5 : ec4);
        if (i + k < end)     out[ea] = 1.0f / (1.0f + expf(-va));
        if (i + 4 + k < end) out[eb] = 1.0f / (1.0f + expf(-vb));
    }
}

// ---------------- launcher ----------------
extern "C" void kernel_launch(void* const* d_in, const int* in_sizes, int n_in,
                              void* d_out, int out_size, void* d_ws, size_t ws_size,
                              hipStream_t stream) {
    const float* emb = (const float*)d_in[0];
    const float* W1  = (const float*)d_in[1];
    const float* b1  = (const float*)d_in[2];
    const float* W2  = (const float*)d_in[3];
    const float* b2  = (const float*)d_in[4];
    const int*   ei  = (const int*)d_in[5];
    const int* src = ei;
    const int* dst = ei + NE;
    float* out = (float*)d_out;

    // workspace layout
    char* w = (char*)d_ws;
    int*   offset      = (int*)w;           w += (size_t)NPAD * 4;
    float* dis         = (float*)w;         w += (size_t)NPAD * 4;
    int*   bucket_base = (int*)w;           w += 1024;
    int*   totals      = (int*)w;           w += 1024;
    int*   blkhist     = (int*)w;           w += (size_t)NB * NBLK * 4;    // 613KB
    int*   csr_src     = (int*)w;           w += (size_t)NE * 4;           // 12.8MB
    int*   csr_eid     = (int*)w;           w += (size_t)NE * 4;           // 12.8MB
    int2*  staged64    = (int2*)w;                                         // 25.6MB
    // after fine_kernel, staged64 is dead; overlay ys/h buffers on it:
    unsigned short* ysbuf = (unsigned short*)w;                            // 12.8MB bf16
    unsigned short* h  = (unsigned short*)(w + (size_t)NE * 4);            // 12.8MB bf16
    unsigned short* ys1 = ysbuf;
    unsigned short* ys2 = ysbuf;                       // overlays dead ys1
    unsigned short* z   = ysbuf + (size_t)NN * 32;     // second half of ysbuf

    // CSR build — LDS atomics only, contiguous staged writes, carries edge ids
    hist_kernel<<<NBLK, 256, 0, stream>>>(dst, blkhist);
    scanA_kernel<<<NB, 64, 0, stream>>>(blkhist, totals);
    scanB_kernel<<<1, 256, 0, stream>>>(totals, bucket_base);
    scatter_kernel<<<NBLK, 256, 0, stream>>>(src, dst, blkhist, bucket_base, staged64);
    fine_kernel<<<NB, 256, 0, stream>>>(staged64, bucket_base, offset, dis, csr_src, csr_eid);

    // layer 1
    mm1_kernel<<<391, 256, 0, stream>>>(emb, W1, dis, ys1);
    agg64_kernel<<<(NN * 8) / 256, 256, 0, stream>>>((const uint4v*)ys1, dis, offset, csr_src, b1, (uint4v*)h);

    // layer 2
    mm2_kernel<<<391, 256, 0, stream>>>(h, W2, dis, ys2);
    agg32_kernel<<<(NN * 4 + 255) / 256, 256, 0, stream>>>((const uint4v*)ys2, dis, offset, csr_src, b2, (uint4v*)z);

    // decode in CSR order: z[dst] in regs, gather only z[src], scatter out[eid]
    decode_csr_kernel<<<(NN * 4 + 255) / 256, 256, 0, stream>>>((const uint4v*)z, offset, csr_src, csr_eid, out);
}

// Round 6
// 415.047 us; speedup vs baseline: 1.1837x; 1.1837x over previous
//
#include <hip/hip_runtime.h>
#include <hip/hip_bf16.h>
#include <math.h>

#define NN 100000
#define NE 3200000
#define NPAD 100096
#define NB 782        // buckets: dst>>7, 128 nodes each
#define BN 128        // nodes per bucket
#define EPB 4096      // edges per block in hist/scatter passes
#define NBLK 782      // ceil(NE/EPB)

typedef __attribute__((ext_vector_type(8))) short short8;
typedef __attribute__((ext_vector_type(4))) float floatx4;
typedef __attribute__((ext_vector_type(4))) unsigned uint4v;

// ---------------- bf16 helpers (storage bf16, math fp32) ----------------
__device__ __forceinline__ unsigned short bf16_of(float x) {
    __hip_bfloat16 h = __float2bfloat16(x);  // RNE
    return *(unsigned short*)&h;
}
__device__ __forceinline__ unsigned pack2(float a, float b) {
    return (unsigned)bf16_of(a) | ((unsigned)bf16_of(b) << 16);
}
__device__ __forceinline__ float lo_f(unsigned u) { return __uint_as_float(u << 16); }
__device__ __forceinline__ float hi_f(unsigned u) { return __uint_as_float(u & 0xffff0000u); }
__device__ __forceinline__ void acc8(float* a, uint4v r) {
    a[0] += lo_f(r[0]); a[1] += hi_f(r[0]);
    a[2] += lo_f(r[1]); a[3] += hi_f(r[1]);
    a[4] += lo_f(r[2]); a[5] += hi_f(r[2]);
    a[6] += lo_f(r[3]); a[7] += hi_f(r[3]);
}

// ---------------- pass A: per-block bucket histogram (bucket-major out) ----------------
__global__ __launch_bounds__(256) void hist_kernel(const int* __restrict__ dst,
                                                   int* __restrict__ blkhist) {
    __shared__ int cnt[NB];
    int t = threadIdx.x;
    for (int i = t; i < NB; i += 256) cnt[i] = 0;
    __syncthreads();
    int e0 = blockIdx.x * EPB;
    int e1 = min(e0 + EPB, NE);
    for (int e = e0 + t; e < e1; e += 256) atomicAdd(&cnt[dst[e] >> 7], 1);
    __syncthreads();
    for (int i = t; i < NB; i += 256) blkhist[i * NBLK + blockIdx.x] = cnt[i];
}

// ---------------- pass B1: per-bucket exclusive scan along blocks ----------------
__global__ __launch_bounds__(64) void scanA_kernel(int* __restrict__ blkhist,
                                                   int* __restrict__ totals) {
    int j = blockIdx.x, lane = threadIdx.x;
    int base = j * NBLK;
    int carry = 0;
    for (int c = 0; c < NBLK; c += 64) {
        int b = c + lane;
        int v = (b < NBLK) ? blkhist[base + b] : 0;
        int inc = v;
#pragma unroll
        for (int m = 1; m < 64; m <<= 1) {
            int u = __shfl_up(inc, m, 64);
            if (lane >= m) inc += u;
        }
        if (b < NBLK) blkhist[base + b] = carry + inc - v;
        carry += __shfl(inc, 63, 64);
    }
    if (lane == 0) totals[j] = carry;
}

// ---------------- pass B2: bucket bases ----------------
__global__ __launch_bounds__(256) void scanB_kernel(const int* __restrict__ totals,
                                                    int* __restrict__ bucket_base) {
    __shared__ int sm[NB];
    int t = threadIdx.x;
    for (int i = t; i < NB; i += 256) sm[i] = totals[i];
    __syncthreads();
    if (t == 0) {
        int r = 0;
        for (int i = 0; i < NB; ++i) { bucket_base[i] = r; r += sm[i]; }
        bucket_base[NB] = r;
    }
}

// ---------------- pass C: LDS-staged scatter -> contiguous run writes ----------------
__global__ __launch_bounds__(256) void scatter_kernel(const int* __restrict__ src,
                                                      const int* __restrict__ dst,
                                                      const int* __restrict__ blkhist,
                                                      const int* __restrict__ bucket_base,
                                                      int* __restrict__ staged) {
    __shared__ int cnt[NB];                 // 3.1KB
    __shared__ int lbase[NB + 1];
    __shared__ int gbase[NB];
    __shared__ int sbuf[EPB];               // 16KB: (src<<7)|dlow
    __shared__ unsigned short sbkt[EPB];    // 8KB: bucket id per slot
    __shared__ int wtot[4];
    int t = threadIdx.x;
    for (int i = t; i < NB; i += 256) cnt[i] = 0;
    __syncthreads();
    int e0 = blockIdx.x * EPB;
    int e1 = min(e0 + EPB, NE);
    int cn = e1 - e0;
    for (int e = e0 + t; e < e1; e += 256) atomicAdd(&cnt[dst[e] >> 7], 1);
    __syncthreads();
    {   // exclusive scan of NB counts across all 256 threads, 4 buckets/thread
        int v[4]; int s = 0;
#pragma unroll
        for (int k = 0; k < 4; ++k) { int idx = t * 4 + k; v[k] = (idx < NB) ? cnt[idx] : 0; s += v[k]; }
        int lane = t & 63, wv = t >> 6;
        int inc = s;
#pragma unroll
        for (int m = 1; m < 64; m <<= 1) {
            int u = __shfl_up(inc, m, 64);
            if (lane >= m) inc += u;
        }
        if (lane == 63) wtot[wv] = inc;
        __syncthreads();
        int wbase = 0;
        for (int w = 0; w < wv; ++w) wbase += wtot[w];
        int run = wbase + inc - s;
#pragma unroll
        for (int k = 0; k < 4; ++k) { int idx = t * 4 + k; if (idx < NB) lbase[idx] = run; run += v[k]; }
        if (t == 255) lbase[NB] = run;  // == cn
    }
    __syncthreads();
    for (int i = t; i < NB; i += 256) {
        gbase[i] = bucket_base[i] + blkhist[i * NBLK + blockIdx.x];
        cnt[i] = lbase[i];            // rank cursors
    }
    __syncthreads();
    for (int e = e0 + t; e < e1; e += 256) {
        int s = src[e], d = dst[e];
        int bk = d >> 7;
        int r = atomicAdd(&cnt[bk], 1);     // LDS atomic
        sbuf[r] = (s << 7) | (d & (BN - 1));
        sbkt[r] = (unsigned short)bk;
    }
    __syncthreads();
    for (int i = t; i < cn; i += 256) {     // contiguous run write-out
        int bk = sbkt[i];
        staged[gbase[bk] + i - lbase[bk]] = sbuf[i];
    }
}

// ---------------- pass D: per-bucket fine counting sort + offsets + dis ----------------
__global__ __launch_bounds__(256) void fine_kernel(const int* __restrict__ staged,
                                                   const int* __restrict__ bucket_base,
                                                   int* __restrict__ offset,
                                                   float* __restrict__ dis,
                                                   int* __restrict__ csr_src) {
    __shared__ int hist[BN];
    __shared__ int offs[BN];
    __shared__ int cur[BN];
    int t = threadIdx.x, j = blockIdx.x;
    int bb = bucket_base[j], be = bucket_base[j + 1];
    for (int i = t; i < BN; i += 256) hist[i] = 0;
    __syncthreads();
    for (int e = bb + t; e < be; e += 256) atomicAdd(&hist[staged[e] & (BN - 1)], 1);
    __syncthreads();
    if (t < 64) {  // wave0: exclusive scan of 128 counts, 2 per lane
        int v[2]; int s = 0;
#pragma unroll
        for (int k = 0; k < 2; ++k) { v[k] = hist[t * 2 + k]; s += v[k]; }
        int inc = s;
#pragma unroll
        for (int m = 1; m < 64; m <<= 1) {
            int u = __shfl_up(inc, m, 64);
            if (t >= m) inc += u;
        }
        int run = inc - s;
#pragma unroll
        for (int k = 0; k < 2; ++k) { offs[t * 2 + k] = run; run += v[k]; }
    }
    __syncthreads();
    for (int l = t; l < BN; l += 256) {
        cur[l] = offs[l];
        int n = j * BN + l;
        if (n < NN) {
            offset[n] = bb + offs[l];
            dis[n] = rsqrtf((float)hist[l] + 1.0f);
        }
    }
    if (j == NB - 1 && t == 0) offset[NN] = NE;
    __syncthreads();
    for (int e = bb + t; e < be; e += 256) {
        int p = staged[e];
        int r = atomicAdd(&cur[p & (BN - 1)], 1);  // LDS atomic
        csr_src[bb + r] = p >> 7;
    }
}

// ---------------- matmul 1 (MFMA): ys1 = bf16(dis * (x @ W1)) ----------------
__global__ __launch_bounds__(256) void mm1_kernel(const float* __restrict__ x,
                                                  const float* __restrict__ W,
                                                  const float* __restrict__ dis,
                                                  unsigned short* __restrict__ y) {
    __shared__ unsigned short Wt[64][136];  // W^T bf16: [n][k], pad 8 shorts
    int t = threadIdx.x;
    for (int i = t; i < 128 * 64; i += 256) {
        int k = i >> 6, n = i & 63;
        Wt[n][k] = bf16_of(W[i]);
    }
    __syncthreads();
    int wave = t >> 6, lane = t & 63;
    int quad = lane >> 4, n16 = lane & 15;
    short8 bfr[4][4];  // [kstep][coltile]
#pragma unroll
    for (int s = 0; s < 4; ++s)
#pragma unroll
        for (int tt = 0; tt < 4; ++tt)
            bfr[s][tt] = *(const short8*)&Wt[tt * 16 + n16][s * 32 + quad * 8];
    int tile0 = (blockIdx.x * 4 + wave) * 4;
#pragma unroll 1
    for (int it = 0; it < 4; ++it) {
        int tile = tile0 + it;
        if (tile >= 6250) break;
        int m0 = tile * 16;
        const float* xp = x + (size_t)(m0 + n16) * 128 + quad * 8;
        floatx4 acc0 = {0,0,0,0}, acc1 = {0,0,0,0}, acc2 = {0,0,0,0}, acc3 = {0,0,0,0};
#pragma unroll
        for (int s = 0; s < 4; ++s) {
            float4 lo = *(const float4*)(xp + s * 32);
            float4 hi = *(const float4*)(xp + s * 32 + 4);
            short8 a;
            a[0] = (short)bf16_of(lo.x); a[1] = (short)bf16_of(lo.y);
            a[2] = (short)bf16_of(lo.z); a[3] = (short)bf16_of(lo.w);
            a[4] = (short)bf16_of(hi.x); a[5] = (short)bf16_of(hi.y);
            a[6] = (short)bf16_of(hi.z); a[7] = (short)bf16_of(hi.w);
            acc0 = __builtin_amdgcn_mfma_f32_16x16x32_bf16(a, bfr[s][0], acc0, 0, 0, 0);
            acc1 = __builtin_amdgcn_mfma_f32_16x16x32_bf16(a, bfr[s][1], acc1, 0, 0, 0);
            acc2 = __builtin_amdgcn_mfma_f32_16x16x32_bf16(a, bfr[s][2], acc2, 0, 0, 0);
            acc3 = __builtin_amdgcn_mfma_f32_16x16x32_bf16(a, bfr[s][3], acc3, 0, 0, 0);
        }
#pragma unroll
        for (int r = 0; r < 4; ++r) {
            int ro = m0 + quad * 4 + r;
            float sc = dis[ro];
            unsigned short* yp = y + (size_t)ro * 64 + n16;
            yp[0]  = bf16_of(acc0[r] * sc);
            yp[16] = bf16_of(acc1[r] * sc);
            yp[32] = bf16_of(acc2[r] * sc);
            yp[48] = bf16_of(acc3[r] * sc);
        }
    }
}

// ---------------- matmul 2 (MFMA): ys2 = bf16(dis * (h @ W2)), h bf16 ----------------
__global__ __launch_bounds__(256) void mm2_kernel(const unsigned short* __restrict__ h,
                                                  const float* __restrict__ W,
                                                  const float* __restrict__ dis,
                                                  unsigned short* __restrict__ y) {
    __shared__ unsigned short Wt[32][72];  // W^T bf16: [n][k], pad 8
    int t = threadIdx.x;
    for (int i = t; i < 64 * 32; i += 256) {
        int k = i >> 5, n = i & 31;
        Wt[n][k] = bf16_of(W[i]);
    }
    __syncthreads();
    int wave = t >> 6, lane = t & 63;
    int quad = lane >> 4, n16 = lane & 15;
    short8 bfr[2][2];
#pragma unroll
    for (int s = 0; s < 2; ++s)
#pragma unroll
        for (int tt = 0; tt < 2; ++tt)
            bfr[s][tt] = *(const short8*)&Wt[tt * 16 + n16][s * 32 + quad * 8];
    int tile0 = (blockIdx.x * 4 + wave) * 4;
#pragma unroll 1
    for (int it = 0; it < 4; ++it) {
        int tile = tile0 + it;
        if (tile >= 6250) break;
        int m0 = tile * 16;
        const unsigned short* hp = h + (size_t)(m0 + n16) * 64 + quad * 8;
        floatx4 acc0 = {0,0,0,0}, acc1 = {0,0,0,0};
#pragma unroll
        for (int s = 0; s < 2; ++s) {
            short8 a = *(const short8*)(hp + s * 32);
            acc0 = __builtin_amdgcn_mfma_f32_16x16x32_bf16(a, bfr[s][0], acc0, 0, 0, 0);
            acc1 = __builtin_amdgcn_mfma_f32_16x16x32_bf16(a, bfr[s][1], acc1, 0, 0, 0);
        }
#pragma unroll
        for (int r = 0; r < 4; ++r) {
            int ro = m0 + quad * 4 + r;
            float sc = dis[ro];
            unsigned short* yp = y + (size_t)ro * 32 + n16;
            yp[0]  = bf16_of(acc0[r] * sc);
            yp[16] = bf16_of(acc1[r] * sc);
        }
    }
}

// ---------------- fused gather-aggregate, dim 64 bf16 -> h bf16 ----------------
// Pipelined: clamped-index batches of 8 gathers (no serial tail); next batch's
// csr indices loaded while current gathers are in flight; predicated accumulate.
__global__ __launch_bounds__(256) void agg64_kernel(const uint4v* __restrict__ ys4,
                                                    const float* __restrict__ dis,
                                                    const int* __restrict__ offset,
                                                    const int* __restrict__ csr_src,
                                                    const float* __restrict__ b,
                                                    uint4v* __restrict__ h4) {
    int tid = blockIdx.x * 256 + threadIdx.x;
    int nd = tid >> 3, c = tid & 7;
    if (nd >= NN) return;
    int start = offset[nd], end = offset[nd + 1];
    float acc[8] = {0, 0, 0, 0, 0, 0, 0, 0};
    acc8(acc, ys4[(size_t)nd * 8 + c]);  // self-loop term
    if (start < end) {
        int last = end - 1;
        int sk[8];
#pragma unroll
        for (int k = 0; k < 8; ++k) sk[k] = csr_src[min(start + k, last)];
        for (int i = start; i < end; i += 8) {
            uint4v r0 = ys4[(size_t)sk[0] * 8 + c];
            uint4v r1 = ys4[(size_t)sk[1] * 8 + c];
            uint4v r2 = ys4[(size_t)sk[2] * 8 + c];
            uint4v r3 = ys4[(size_t)sk[3] * 8 + c];
            uint4v r4 = ys4[(size_t)sk[4] * 8 + c];
            uint4v r5 = ys4[(size_t)sk[5] * 8 + c];
            uint4v r6 = ys4[(size_t)sk[6] * 8 + c];
            uint4v r7 = ys4[(size_t)sk[7] * 8 + c];
            int i2 = i + 8;
            if (i2 < end) {
#pragma unroll
                for (int k = 0; k < 8; ++k) sk[k] = csr_src[min(i2 + k, last)];
            }
            int rem = end - i;  // >= 1
            acc8(acc, r0);
            if (rem > 1) acc8(acc, r1);
            if (rem > 2) acc8(acc, r2);
            if (rem > 3) acc8(acc, r3);
            if (rem > 4) acc8(acc, r4);
            if (rem > 5) acc8(acc, r5);
            if (rem > 6) acc8(acc, r6);
            if (rem > 7) acc8(acc, r7);
        }
    }
    float ds = dis[nd];
    const float4 bv0 = *(const float4*)&b[c * 8];
    const float4 bv1 = *(const float4*)&b[c * 8 + 4];
    uint4v o;
    o[0] = pack2(fmaxf(fmaf(ds, acc[0], bv0.x), 0.f), fmaxf(fmaf(ds, acc[1], bv0.y), 0.f));
    o[1] = pack2(fmaxf(fmaf(ds, acc[2], bv0.z), 0.f), fmaxf(fmaf(ds, acc[3], bv0.w), 0.f));
    o[2] = pack2(fmaxf(fmaf(ds, acc[4], bv1.x), 0.f), fmaxf(fmaf(ds, acc[5], bv1.y), 0.f));
    o[3] = pack2(fmaxf(fmaf(ds, acc[6], bv1.z), 0.f), fmaxf(fmaf(ds, acc[7], bv1.w), 0.f));
    h4[(size_t)nd * 8 + c] = o;
}

// ---------------- fused gather-aggregate, dim 32 bf16 -> z bf16 ----------------
__global__ __launch_bounds__(256) void agg32_kernel(const uint4v* __restrict__ ys4,
                                                    const float* __restrict__ dis,
                                                    const int* __restrict__ offset,
                                                    const int* __restrict__ csr_src,
                                                    const float* __restrict__ b,
                                                    uint4v* __restrict__ z4) {
    int tid = blockIdx.x * 256 + threadIdx.x;
    int nd = tid >> 2, c = tid & 3;
    if (nd >= NN) return;
    int start = offset[nd], end = offset[nd + 1];
    float acc[8] = {0, 0, 0, 0, 0, 0, 0, 0};
    acc8(acc, ys4[(size_t)nd * 4 + c]);
    if (start < end) {
        int last = end - 1;
        int sk[8];
#pragma unroll
        for (int k = 0; k < 8; ++k) sk[k] = csr_src[min(start + k, last)];
        for (int i = start; i < end; i += 8) {
            uint4v r0 = ys4[(size_t)sk[0] * 4 + c];
            uint4v r1 = ys4[(size_t)sk[1] * 4 + c];
            uint4v r2 = ys4[(size_t)sk[2] * 4 + c];
            uint4v r3 = ys4[(size_t)sk[3] * 4 + c];
            uint4v r4 = ys4[(size_t)sk[4] * 4 + c];
            uint4v r5 = ys4[(size_t)sk[5] * 4 + c];
            uint4v r6 = ys4[(size_t)sk[6] * 4 + c];
            uint4v r7 = ys4[(size_t)sk[7] * 4 + c];
            int i2 = i + 8;
            if (i2 < end) {
#pragma unroll
                for (int k = 0; k < 8; ++k) sk[k] = csr_src[min(i2 + k, last)];
            }
            int rem = end - i;
            acc8(acc, r0);
            if (rem > 1) acc8(acc, r1);
            if (rem > 2) acc8(acc, r2);
            if (rem > 3) acc8(acc, r3);
            if (rem > 4) acc8(acc, r4);
            if (rem > 5) acc8(acc, r5);
            if (rem > 6) acc8(acc, r6);
            if (rem > 7) acc8(acc, r7);
        }
    }
    float ds = dis[nd];
    const float4 bv0 = *(const float4*)&b[c * 8];
    const float4 bv1 = *(const float4*)&b[c * 8 + 4];
    uint4v o;
    o[0] = pack2(fmaf(ds, acc[0], bv0.x), fmaf(ds, acc[1], bv0.y));
    o[1] = pack2(fmaf(ds, acc[2], bv0.z), fmaf(ds, acc[3], bv0.w));
    o[2] = pack2(fmaf(ds, acc[4], bv1.x), fmaf(ds, acc[5], bv1.y));
    o[3] = pack2(fmaf(ds, acc[6], bv1.z), fmaf(ds, acc[7], bv1.w));
    z4[(size_t)nd * 4 + c] = o;
}

// ---------------- decode: sigmoid(dot(z[src], z[dst])), 4 lanes/edge, bf16 z ---------
__global__ __launch_bounds__(256) void decode_kernel(const uint4v* __restrict__ z4,
                                                     const int* __restrict__ src,
                                                     const int* __restrict__ dst,
                                                     float* __restrict__ out) {
    int tid = blockIdx.x * 256 + threadIdx.x;
    int e = tid >> 2, k = tid & 3;
    if (e >= NE) return;
    int s = src[e], d = dst[e];
    uint4v ra = z4[(size_t)s * 4 + k];
    uint4v rb = z4[(size_t)d * 4 + k];
    float acc;
    acc  = lo_f(ra[0]) * lo_f(rb[0]) + hi_f(ra[0]) * hi_f(rb[0]);
    acc += lo_f(ra[1]) * lo_f(rb[1]) + hi_f(ra[1]) * hi_f(rb[1]);
    acc += lo_f(ra[2]) * lo_f(rb[2]) + hi_f(ra[2]) * hi_f(rb[2]);
    acc += lo_f(ra[3]) * lo_f(rb[3]) + hi_f(ra[3]) * hi_f(rb[3]);
#pragma unroll
    for (int m = 2; m >= 1; m >>= 1) acc += __shfl_xor(acc, m, 4);
    if (k == 0) out[e] = 1.0f / (1.0f + expf(-acc));
}

// ---------------- launcher ----------------
extern "C" void kernel_launch(void* const* d_in, const int* in_sizes, int n_in,
                              void* d_out, int out_size, void* d_ws, size_t ws_size,
                              hipStream_t stream) {
    const float* emb = (const float*)d_in[0];
    const float* W1  = (const float*)d_in[1];
    const float* b1  = (const float*)d_in[2];
    const float* W2  = (const float*)d_in[3];
    const float* b2  = (const float*)d_in[4];
    const int*   ei  = (const int*)d_in[5];
    const int* src = ei;
    const int* dst = ei + NE;
    float* out = (float*)d_out;

    // workspace layout
    char* w = (char*)d_ws;
    int*   offset      = (int*)w;           w += (size_t)NPAD * 4;
    float* dis         = (float*)w;         w += (size_t)NPAD * 4;
    int*   bucket_base = (int*)w;           w += 4096;                     // NB+1 ints
    int*   totals      = (int*)w;           w += 4096;
    int*   blkhist     = (int*)w;           w += (size_t)NB * NBLK * 4;    // 2.45MB
    int*   csr_src     = (int*)w;           w += (size_t)NE * 4;           // 12.8MB
    int*   staged      = (int*)w;           w += (size_t)NE * 4;           // 12.8MB packed
    unsigned short* ysbuf = (unsigned short*)w; w += (size_t)NN * 64 * 2;  // 12.8MB bf16
    unsigned short* h  = (unsigned short*)w;                               // 12.8MB bf16
    unsigned short* ys1 = ysbuf;
    unsigned short* ys2 = ysbuf;                       // overlays dead ys1
    unsigned short* z   = ysbuf + (size_t)NN * 32;     // second half of ysbuf

    // CSR build — LDS atomics only, contiguous staged writes
    hist_kernel<<<NBLK, 256, 0, stream>>>(dst, blkhist);
    scanA_kernel<<<NB, 64, 0, stream>>>(blkhist, totals);
    scanB_kernel<<<1, 256, 0, stream>>>(totals, bucket_base);
    scatter_kernel<<<NBLK, 256, 0, stream>>>(src, dst, blkhist, bucket_base, staged);
    fine_kernel<<<NB, 256, 0, stream>>>(staged, bucket_base, offset, dis, csr_src);

    // layer 1
    mm1_kernel<<<391, 256, 0, stream>>>(emb, W1, dis, ys1);
    agg64_kernel<<<(NN * 8) / 256, 256, 0, stream>>>((const uint4v*)ys1, dis, offset, csr_src, b1, (uint4v*)h);

    // layer 2
    mm2_kernel<<<391, 256, 0, stream>>>(h, W2, dis, ys2);
    agg32_kernel<<<(NN * 4 + 255) / 256, 256, 0, stream>>>((const uint4v*)ys2, dis, offset, csr_src, b2, (uint4v*)z);

    // decode
    decode_kernel<<<(NE * 4) / 256, 256, 0, stream>>>((const uint4v*)z, src, dst, out);
}

// Round 7
// 351.852 us; speedup vs baseline: 1.3963x; 1.1796x over previous
//
#include <hip/hip_runtime.h>
#include <hip/hip_bf16.h>
#include <math.h>

#define NN 100000
#define NE 3200000
#define NPAD 100096
#define NB 196        // buckets: dst>>9, 512 nodes each
#define BN 512        // nodes per bucket
#define EPB 8192      // edges per block in hist/scatter passes
#define NBLK 391      // ceil(NE/EPB)

typedef __attribute__((ext_vector_type(8))) short short8;
typedef __attribute__((ext_vector_type(4))) float floatx4;
typedef __attribute__((ext_vector_type(4))) unsigned uint4v;

// ---------------- bf16 helpers (storage bf16, math fp32) ----------------
__device__ __forceinline__ unsigned short bf16_of(float x) {
    __hip_bfloat16 h = __float2bfloat16(x);  // RNE
    return *(unsigned short*)&h;
}
__device__ __forceinline__ unsigned pack2(float a, float b) {
    return (unsigned)bf16_of(a) | ((unsigned)bf16_of(b) << 16);
}
__device__ __forceinline__ float lo_f(unsigned u) { return __uint_as_float(u << 16); }
__device__ __forceinline__ float hi_f(unsigned u) { return __uint_as_float(u & 0xffff0000u); }
__device__ __forceinline__ void acc8(float* a, uint4v r) {
    a[0] += lo_f(r[0]); a[1] += hi_f(r[0]);
    a[2] += lo_f(r[1]); a[3] += hi_f(r[1]);
    a[4] += lo_f(r[2]); a[5] += hi_f(r[2]);
    a[6] += lo_f(r[3]); a[7] += hi_f(r[3]);
}

// ---------------- pass A: per-block bucket histogram (bucket-major out) ----------------
__global__ __launch_bounds__(256) void hist_kernel(const int* __restrict__ dst,
                                                   int* __restrict__ blkhist) {
    __shared__ int cnt[NB];
    int t = threadIdx.x;
    for (int i = t; i < NB; i += 256) cnt[i] = 0;
    __syncthreads();
    int e0 = blockIdx.x * EPB;
    int e1 = min(e0 + EPB, NE);
    for (int e = e0 + t; e < e1; e += 256) atomicAdd(&cnt[dst[e] >> 9], 1);
    __syncthreads();
    for (int i = t; i < NB; i += 256) blkhist[i * NBLK + blockIdx.x] = cnt[i];
}

// ---------------- pass B: per-bucket exclusive scan along blocks ----------------
__global__ __launch_bounds__(64) void scanA_kernel(int* __restrict__ blkhist,
                                                   int* __restrict__ totals) {
    int j = blockIdx.x, lane = threadIdx.x;
    int base = j * NBLK;
    int carry = 0;
    for (int c = 0; c < NBLK; c += 64) {
        int b = c + lane;
        int v = (b < NBLK) ? blkhist[base + b] : 0;
        int inc = v;
#pragma unroll
        for (int m = 1; m < 64; m <<= 1) {
            int u = __shfl_up(inc, m, 64);
            if (lane >= m) inc += u;
        }
        if (b < NBLK) blkhist[base + b] = carry + inc - v;
        carry += __shfl(inc, 63, 64);
    }
    if (lane == 0) totals[j] = carry;
}

// ---------------- pass C: LDS-staged scatter -> contiguous run writes ----------------
// bucket_base is computed in-block from totals (scanB kernel eliminated).
__global__ __launch_bounds__(256) void scatter_kernel(const int* __restrict__ src,
                                                      const int* __restrict__ dst,
                                                      const int* __restrict__ blkhist,
                                                      const int* __restrict__ totals,
                                                      int* __restrict__ staged) {
    __shared__ int cnt[NB];
    __shared__ int lbase[NB + 1];
    __shared__ int gbase[NB];
    __shared__ int bbase[NB];
    __shared__ int sbuf[EPB];             // 32KB
    __shared__ unsigned char sbkt[EPB];   // 8KB: bucket id per slot
    int t = threadIdx.x;
    for (int i = t; i < NB; i += 256) cnt[i] = 0;
    __syncthreads();
    int e0 = blockIdx.x * EPB;
    int e1 = min(e0 + EPB, NE);
    int cn = e1 - e0;
    for (int e = e0 + t; e < e1; e += 256) atomicAdd(&cnt[dst[e] >> 9], 1);
    __syncthreads();
    if (t < 64) {  // exclusive scan of 196 block-local counts, 4 per lane
        int v[4]; int s = 0;
#pragma unroll
        for (int k = 0; k < 4; ++k) { int idx = t * 4 + k; v[k] = (idx < NB) ? cnt[idx] : 0; s += v[k]; }
        int inc = s;
#pragma unroll
        for (int m = 1; m < 64; m <<= 1) {
            int u = __shfl_up(inc, m, 64);
            if (t >= m) inc += u;
        }
        int run = inc - s;
#pragma unroll
        for (int k = 0; k < 4; ++k) { int idx = t * 4 + k; if (idx < NB) lbase[idx] = run; run += v[k]; }
        if (t == 63) lbase[NB] = inc;  // == cn
        // exclusive scan of bucket totals -> bucket bases (replaces scanB)
        int v2[4]; int s2 = 0;
#pragma unroll
        for (int k = 0; k < 4; ++k) { int idx = t * 4 + k; v2[k] = (idx < NB) ? totals[idx] : 0; s2 += v2[k]; }
        int inc2 = s2;
#pragma unroll
        for (int m = 1; m < 64; m <<= 1) {
            int u = __shfl_up(inc2, m, 64);
            if (t >= m) inc2 += u;
        }
        int run2 = inc2 - s2;
#pragma unroll
        for (int k = 0; k < 4; ++k) { int idx = t * 4 + k; if (idx < NB) bbase[idx] = run2; run2 += v2[k]; }
    }
    __syncthreads();
    for (int i = t; i < NB; i += 256) {
        gbase[i] = bbase[i] + blkhist[i * NBLK + blockIdx.x];
        cnt[i] = lbase[i];            // rank cursors
    }
    __syncthreads();
    for (int e = e0 + t; e < e1; e += 256) {
        int s = src[e], d = dst[e];
        int bk = d >> 9;
        int r = atomicAdd(&cnt[bk], 1);     // LDS atomic
        sbuf[r] = (s << 9) | (d & (BN - 1));
        sbkt[r] = (unsigned char)bk;
    }
    __syncthreads();
    for (int i = t; i < cn; i += 256) {     // contiguous run write-out
        int bk = sbkt[i];
        staged[gbase[bk] + i - lbase[bk]] = sbuf[i];
    }
}

// ---------------- pass D: per-bucket fine counting sort + offsets + dis ----------------
__global__ __launch_bounds__(256) void fine_kernel(const int* __restrict__ staged,
                                                   const int* __restrict__ totals,
                                                   int* __restrict__ offset,
                                                   float* __restrict__ dis,
                                                   int* __restrict__ csr_src) {
    __shared__ int hist[BN];
    __shared__ int offs[BN];
    __shared__ int cur[BN];
    __shared__ int bbase[NB + 1];
    int t = threadIdx.x, j = blockIdx.x;
    if (t < 64) {  // exclusive scan of bucket totals (replaces scanB)
        int v2[4]; int s2 = 0;
#pragma unroll
        for (int k = 0; k < 4; ++k) { int idx = t * 4 + k; v2[k] = (idx < NB) ? totals[idx] : 0; s2 += v2[k]; }
        int inc2 = s2;
#pragma unroll
        for (int m = 1; m < 64; m <<= 1) {
            int u = __shfl_up(inc2, m, 64);
            if (t >= m) inc2 += u;
        }
        int run2 = inc2 - s2;
#pragma unroll
        for (int k = 0; k < 4; ++k) { int idx = t * 4 + k; if (idx < NB) bbase[idx] = run2; run2 += v2[k]; }
        if (t == 63) bbase[NB] = inc2;   // == NE
    }
    for (int i = t; i < BN; i += 256) hist[i] = 0;
    __syncthreads();
    int bb = bbase[j], be = bbase[j + 1];
    for (int e = bb + t; e < be; e += 256) atomicAdd(&hist[staged[e] & (BN - 1)], 1);
    __syncthreads();
    if (t < 64) {  // wave0: exclusive scan of 512 counts
        int v[8]; int s = 0;
#pragma unroll
        for (int k = 0; k < 8; ++k) { v[k] = hist[t * 8 + k]; s += v[k]; }
        int inc = s;
#pragma unroll
        for (int m = 1; m < 64; m <<= 1) {
            int u = __shfl_up(inc, m, 64);
            if (t >= m) inc += u;
        }
        int run = inc - s;
#pragma unroll
        for (int k = 0; k < 8; ++k) { offs[t * 8 + k] = run; run += v[k]; }
    }
    __syncthreads();
    for (int l = t; l < BN; l += 256) {
        cur[l] = offs[l];
        int n = j * BN + l;
        if (n < NN) {
            offset[n] = bb + offs[l];
            dis[n] = rsqrtf((float)hist[l] + 1.0f);
        }
    }
    if (j == NB - 1 && t == 0) offset[NN] = NE;
    __syncthreads();
    for (int e = bb + t; e < be; e += 256) {
        int p = staged[e];
        int r = atomicAdd(&cur[p & (BN - 1)], 1);  // LDS atomic
        csr_src[bb + r] = p >> 9;
    }
}

// ---------------- matmul 1 (MFMA): ys1 = bf16(dis * (x @ W1)) ----------------
__global__ __launch_bounds__(256) void mm1_kernel(const float* __restrict__ x,
                                                  const float* __restrict__ W,
                                                  const float* __restrict__ dis,
                                                  unsigned short* __restrict__ y) {
    __shared__ unsigned short Wt[64][136];  // W^T bf16: [n][k], pad 8 shorts
    int t = threadIdx.x;
    for (int i = t; i < 128 * 64; i += 256) {
        int k = i >> 6, n = i & 63;
        Wt[n][k] = bf16_of(W[i]);
    }
    __syncthreads();
    int wave = t >> 6, lane = t & 63;
    int quad = lane >> 4, n16 = lane & 15;
    short8 bfr[4][4];  // [kstep][coltile]
#pragma unroll
    for (int s = 0; s < 4; ++s)
#pragma unroll
        for (int tt = 0; tt < 4; ++tt)
            bfr[s][tt] = *(const short8*)&Wt[tt * 16 + n16][s * 32 + quad * 8];
    int tile0 = (blockIdx.x * 4 + wave) * 4;
#pragma unroll 1
    for (int it = 0; it < 4; ++it) {
        int tile = tile0 + it;
        if (tile >= 6250) break;
        int m0 = tile * 16;
        const float* xp = x + (size_t)(m0 + n16) * 128 + quad * 8;
        floatx4 acc0 = {0,0,0,0}, acc1 = {0,0,0,0}, acc2 = {0,0,0,0}, acc3 = {0,0,0,0};
#pragma unroll
        for (int s = 0; s < 4; ++s) {
            float4 lo = *(const float4*)(xp + s * 32);
            float4 hi = *(const float4*)(xp + s * 32 + 4);
            short8 a;
            a[0] = (short)bf16_of(lo.x); a[1] = (short)bf16_of(lo.y);
            a[2] = (short)bf16_of(lo.z); a[3] = (short)bf16_of(lo.w);
            a[4] = (short)bf16_of(hi.x); a[5] = (short)bf16_of(hi.y);
            a[6] = (short)bf16_of(hi.z); a[7] = (short)bf16_of(hi.w);
            acc0 = __builtin_amdgcn_mfma_f32_16x16x32_bf16(a, bfr[s][0], acc0, 0, 0, 0);
            acc1 = __builtin_amdgcn_mfma_f32_16x16x32_bf16(a, bfr[s][1], acc1, 0, 0, 0);
            acc2 = __builtin_amdgcn_mfma_f32_16x16x32_bf16(a, bfr[s][2], acc2, 0, 0, 0);
            acc3 = __builtin_amdgcn_mfma_f32_16x16x32_bf16(a, bfr[s][3], acc3, 0, 0, 0);
        }
#pragma unroll
        for (int r = 0; r < 4; ++r) {
            int ro = m0 + quad * 4 + r;
            float sc = dis[ro];
            unsigned short* yp = y + (size_t)ro * 64 + n16;
            yp[0]  = bf16_of(acc0[r] * sc);
            yp[16] = bf16_of(acc1[r] * sc);
            yp[32] = bf16_of(acc2[r] * sc);
            yp[48] = bf16_of(acc3[r] * sc);
        }
    }
}

// ---------------- fused layer-1 aggregate + layer-2 matmul ----------------
// Round-0 tail-loop gather (proven 163MB FETCH) producing the fp32 h-row of a
// node across its 8 threads; then z = dis*(h@W2) computed in-VALU via LDS
// h-exchange (padded stride 68 to avoid 8-way bank conflicts); writes ys2
// (32 bf16/node). Eliminates mm2 dispatch, h buffer, and 25.6MB of traffic.
__global__ __launch_bounds__(256) void agg64mm2_kernel(const uint4v* __restrict__ ys4,
                                                       const float* __restrict__ dis,
                                                       const int* __restrict__ offset,
                                                       const int* __restrict__ csr_src,
                                                       const float* __restrict__ b1,
                                                       const float* __restrict__ W2,
                                                       unsigned int* __restrict__ ys2) {
    __shared__ float w2s[64 * 32];      // 8KB fp32, [k][n] row-major
    __shared__ float hbuf[32 * 68];     // 8.5KB: 32 nodes x 64 k, stride 68 (bank-spread)
    int t = threadIdx.x;
    for (int i = t; i < 2048; i += 256) w2s[i] = W2[i];
    __syncthreads();
    int tid = blockIdx.x * 256 + t;
    int nd = tid >> 3, c = tid & 7;     // grid exact: nd < NN always
    int start = offset[nd], end = offset[nd + 1];
    float acc[8] = {0, 0, 0, 0, 0, 0, 0, 0};
    acc8(acc, ys4[(size_t)nd * 8 + c]);  // self-loop term
    int i = start;
    int n8 = start + ((end - start) & ~7);
    for (; i < n8; i += 8) {
        int s0 = csr_src[i],     s1 = csr_src[i + 1], s2 = csr_src[i + 2], s3 = csr_src[i + 3];
        int s4 = csr_src[i + 4], s5 = csr_src[i + 5], s6 = csr_src[i + 6], s7 = csr_src[i + 7];
        uint4v r0 = ys4[(size_t)s0 * 8 + c];
        uint4v r1 = ys4[(size_t)s1 * 8 + c];
        uint4v r2 = ys4[(size_t)s2 * 8 + c];
        uint4v r3 = ys4[(size_t)s3 * 8 + c];
        uint4v r4 = ys4[(size_t)s4 * 8 + c];
        uint4v r5 = ys4[(size_t)s5 * 8 + c];
        uint4v r6 = ys4[(size_t)s6 * 8 + c];
        uint4v r7 = ys4[(size_t)s7 * 8 + c];
        acc8(acc, r0); acc8(acc, r1); acc8(acc, r2); acc8(acc, r3);
        acc8(acc, r4); acc8(acc, r5); acc8(acc, r6); acc8(acc, r7);
    }
    for (; i < end; ++i) acc8(acc, ys4[(size_t)csr_src[i] * 8 + c]);
    float ds = dis[nd];
    const float4 bv0 = *(const float4*)&b1[c * 8];
    const float4 bv1 = *(const float4*)&b1[c * 8 + 4];
    // h row (fp32, bias + relu) -> per-wave LDS exchange (same-wave, no barrier)
    float* hrow = &hbuf[(t >> 3) * 68];
    float4 h0, h1;
    h0.x = fmaxf(fmaf(ds, acc[0], bv0.x), 0.f);
    h0.y = fmaxf(fmaf(ds, acc[1], bv0.y), 0.f);
    h0.z = fmaxf(fmaf(ds, acc[2], bv0.z), 0.f);
    h0.w = fmaxf(fmaf(ds, acc[3], bv0.w), 0.f);
    h1.x = fmaxf(fmaf(ds, acc[4], bv1.x), 0.f);
    h1.y = fmaxf(fmaf(ds, acc[5], bv1.y), 0.f);
    h1.z = fmaxf(fmaf(ds, acc[6], bv1.z), 0.f);
    h1.w = fmaxf(fmaf(ds, acc[7], bv1.w), 0.f);
    *(float4*)&hrow[c * 8]     = h0;
    *(float4*)&hrow[c * 8 + 4] = h1;
    // z[c*4 .. c*4+3] = ds * sum_k h[k] * W2[k][n]
    float p0 = 0.f, p1 = 0.f, p2 = 0.f, p3 = 0.f;
#pragma unroll 8
    for (int k = 0; k < 64; ++k) {
        float hk = hrow[k];
        const float4 wr = *(const float4*)&w2s[k * 32 + c * 4];
        p0 = fmaf(hk, wr.x, p0);
        p1 = fmaf(hk, wr.y, p1);
        p2 = fmaf(hk, wr.z, p2);
        p3 = fmaf(hk, wr.w, p3);
    }
    p0 *= ds; p1 *= ds; p2 *= ds; p3 *= ds;
    unsigned int* zp = ys2 + (size_t)nd * 16 + c * 2;  // 32 bf16 = 16 uints per node
    zp[0] = pack2(p0, p1);
    zp[1] = pack2(p2, p3);
}

// ---------------- fused gather-aggregate, dim 32 bf16 -> z bf16, unroll 8 ----------------
__global__ __launch_bounds__(256) void agg32_kernel(const uint4v* __restrict__ ys4,
                                                    const float* __restrict__ dis,
                                                    const int* __restrict__ offset,
                                                    const int* __restrict__ csr_src,
                                                    const float* __restrict__ b,
                                                    uint4v* __restrict__ z4) {
    int tid = blockIdx.x * 256 + threadIdx.x;
    int nd = tid >> 2, c = tid & 3;
    if (nd >= NN) return;
    int start = offset[nd], end = offset[nd + 1];
    float acc[8] = {0, 0, 0, 0, 0, 0, 0, 0};
    acc8(acc, ys4[(size_t)nd * 4 + c]);
    int i = start;
    int n8 = start + ((end - start) & ~7);
    for (; i < n8; i += 8) {
        int s0 = csr_src[i],     s1 = csr_src[i + 1], s2 = csr_src[i + 2], s3 = csr_src[i + 3];
        int s4 = csr_src[i + 4], s5 = csr_src[i + 5], s6 = csr_src[i + 6], s7 = csr_src[i + 7];
        uint4v r0 = ys4[(size_t)s0 * 4 + c];
        uint4v r1 = ys4[(size_t)s1 * 4 + c];
        uint4v r2 = ys4[(size_t)s2 * 4 + c];
        uint4v r3 = ys4[(size_t)s3 * 4 + c];
        uint4v r4 = ys4[(size_t)s4 * 4 + c];
        uint4v r5 = ys4[(size_t)s5 * 4 + c];
        uint4v r6 = ys4[(size_t)s6 * 4 + c];
        uint4v r7 = ys4[(size_t)s7 * 4 + c];
        acc8(acc, r0); acc8(acc, r1); acc8(acc, r2); acc8(acc, r3);
        acc8(acc, r4); acc8(acc, r5); acc8(acc, r6); acc8(acc, r7);
    }
    for (; i < end; ++i) acc8(acc, ys4[(size_t)csr_src[i] * 4 + c]);
    float ds = dis[nd];
    const float4 bv0 = *(const float4*)&b[c * 8];
    const float4 bv1 = *(const float4*)&b[c * 8 + 4];
    uint4v o;
    o[0] = pack2(fmaf(ds, acc[0], bv0.x), fmaf(ds, acc[1], bv0.y));
    o[1] = pack2(fmaf(ds, acc[2], bv0.z), fmaf(ds, acc[3], bv0.w));
    o[2] = pack2(fmaf(ds, acc[4], bv1.x), fmaf(ds, acc[5], bv1.y));
    o[3] = pack2(fmaf(ds, acc[6], bv1.z), fmaf(ds, acc[7], bv1.w));
    z4[(size_t)nd * 4 + c] = o;
}

// ---------------- decode: sigmoid(dot(z[src], z[dst])), 4 lanes/edge, bf16 z ---------
__global__ __launch_bounds__(256) void decode_kernel(const uint4v* __restrict__ z4,
                                                     const int* __restrict__ src,
                                                     const int* __restrict__ dst,
                                                     float* __restrict__ out) {
    int tid = blockIdx.x * 256 + threadIdx.x;
    int e = tid >> 2, k = tid & 3;
    if (e >= NE) return;
    int s = src[e], d = dst[e];
    uint4v ra = z4[(size_t)s * 4 + k];
    uint4v rb = z4[(size_t)d * 4 + k];
    float acc;
    acc  = lo_f(ra[0]) * lo_f(rb[0]) + hi_f(ra[0]) * hi_f(rb[0]);
    acc += lo_f(ra[1]) * lo_f(rb[1]) + hi_f(ra[1]) * hi_f(rb[1]);
    acc += lo_f(ra[2]) * lo_f(rb[2]) + hi_f(ra[2]) * hi_f(rb[2]);
    acc += lo_f(ra[3]) * lo_f(rb[3]) + hi_f(ra[3]) * hi_f(rb[3]);
#pragma unroll
    for (int m = 2; m >= 1; m >>= 1) acc += __shfl_xor(acc, m, 4);
    if (k == 0) out[e] = 1.0f / (1.0f + expf(-acc));
}

// ---------------- launcher ----------------
extern "C" void kernel_launch(void* const* d_in, const int* in_sizes, int n_in,
                              void* d_out, int out_size, void* d_ws, size_t ws_size,
                              hipStream_t stream) {
    const float* emb = (const float*)d_in[0];
    const float* W1  = (const float*)d_in[1];
    const float* b1  = (const float*)d_in[2];
    const float* W2  = (const float*)d_in[3];
    const float* b2  = (const float*)d_in[4];
    const int*   ei  = (const int*)d_in[5];
    const int* src = ei;
    const int* dst = ei + NE;
    float* out = (float*)d_out;

    // workspace layout
    char* w = (char*)d_ws;
    int*   offset      = (int*)w;           w += (size_t)NPAD * 4;
    float* dis         = (float*)w;         w += (size_t)NPAD * 4;
    int*   totals      = (int*)w;           w += 1024;
    int*   blkhist     = (int*)w;           w += 307200;                  // NB*NBLK ints
    int*   csr_src     = (int*)w;           w += (size_t)NE * 4;          // 12.8MB
    int*   staged      = (int*)w;           w += (size_t)NE * 4;          // 12.8MB packed
    unsigned short* ysbuf = (unsigned short*)w; w += (size_t)NN * 64 * 2; // 12.8MB bf16
    unsigned short* ys2 = (unsigned short*)w;                             // 6.4MB bf16
    unsigned short* ys1 = ysbuf;
    unsigned short* z   = ysbuf;            // overlays dead ys1 after agg64mm2

    // CSR build — LDS atomics only, contiguous staged writes (4 kernels)
    hist_kernel<<<NBLK, 256, 0, stream>>>(dst, blkhist);
    scanA_kernel<<<NB, 64, 0, stream>>>(blkhist, totals);
    scatter_kernel<<<NBLK, 256, 0, stream>>>(src, dst, blkhist, totals, staged);
    fine_kernel<<<NB, 256, 0, stream>>>(staged, totals, offset, dis, csr_src);

    // layer 1 matmul
    mm1_kernel<<<391, 256, 0, stream>>>(emb, W1, dis, ys1);
    // fused: layer-1 aggregate (+bias,relu) + layer-2 matmul -> ys2
    agg64mm2_kernel<<<(NN * 8) / 256, 256, 0, stream>>>((const uint4v*)ys1, dis, offset, csr_src,
                                                        b1, W2, (unsigned int*)ys2);
    // layer-2 aggregate -> z (overlays dead ys1)
    agg32_kernel<<<(NN * 4 + 255) / 256, 256, 0, stream>>>((const uint4v*)ys2, dis, offset, csr_src, b2, (uint4v*)z);

    // decode
    decode_kernel<<<(NE * 4) / 256, 256, 0, stream>>>((const uint4v*)z, src, dst, out);
}

// Round 8
// 321.316 us; speedup vs baseline: 1.5290x; 1.0950x over previous
//
#include <hip/hip_runtime.h>
#include <hip/hip_bf16.h>
#include <math.h>

#define NN 100000
#define NE 3200000
#define NPAD 100096
#define NB 196        // buckets: dst>>9, 512 nodes each
#define BN 512        // nodes per bucket
#define EPB 8192      // edges per block in scatter pass
#define NBLK 391      // ceil(NE/EPB)
#define SLOT 18432    // slab size per bucket (mean 16384 + 16 sigma)

typedef __attribute__((ext_vector_type(8))) short short8;
typedef __attribute__((ext_vector_type(4))) float floatx4;
typedef __attribute__((ext_vector_type(4))) unsigned uint4v;

// ---------------- bf16 helpers (storage bf16, math fp32) ----------------
__device__ __forceinline__ unsigned short bf16_of(float x) {
    __hip_bfloat16 h = __float2bfloat16(x);  // RNE
    return *(unsigned short*)&h;
}
__device__ __forceinline__ unsigned pack2(float a, float b) {
    return (unsigned)bf16_of(a) | ((unsigned)bf16_of(b) << 16);
}
__device__ __forceinline__ float lo_f(unsigned u) { return __uint_as_float(u << 16); }
__device__ __forceinline__ float hi_f(unsigned u) { return __uint_as_float(u & 0xffff0000u); }
__device__ __forceinline__ void acc8(float* a, uint4v r) {
    a[0] += lo_f(r[0]); a[1] += hi_f(r[0]);
    a[2] += lo_f(r[1]); a[3] += hi_f(r[1]);
    a[4] += lo_f(r[2]); a[5] += hi_f(r[2]);
    a[6] += lo_f(r[3]); a[7] += hi_f(r[3]);
}

// ---------------- pass 1: scatter into fixed-stride bucket slabs ----------------
// Each block: LDS count -> in-block scan -> ONE global atomicAdd per bucket to
// reserve a contiguous run in the bucket's slab -> LDS-staged scatter ->
// contiguous run write-out. Replaces hist+scanA+scanB+blkhist entirely.
__global__ __launch_bounds__(512) void scatter_kernel(const int* __restrict__ src,
                                                      const int* __restrict__ dst,
                                                      int* __restrict__ gcur,
                                                      int* __restrict__ staged) {
    __shared__ int cnt[NB];
    __shared__ int lbase[NB + 1];
    __shared__ int gbase[NB];
    __shared__ int sbuf[EPB];             // 32KB: (src<<9)|dlow
    __shared__ unsigned char sbkt[EPB];   // 8KB: bucket id per slot
    int t = threadIdx.x;
    for (int i = t; i < NB; i += 512) cnt[i] = 0;
    __syncthreads();
    int e0 = blockIdx.x * EPB;
    int e1 = min(e0 + EPB, NE);
    int cn = e1 - e0;
    for (int e = e0 + t; e < e1; e += 512) atomicAdd(&cnt[dst[e] >> 9], 1);
    __syncthreads();
    if (t < 64) {  // exclusive scan of 196 local counts, 4 per lane (wave 0)
        int v[4]; int s = 0;
#pragma unroll
        for (int k = 0; k < 4; ++k) { int idx = t * 4 + k; v[k] = (idx < NB) ? cnt[idx] : 0; s += v[k]; }
        int inc = s;
#pragma unroll
        for (int m = 1; m < 64; m <<= 1) {
            int u = __shfl_up(inc, m, 64);
            if (t >= m) inc += u;
        }
        int run = inc - s;
#pragma unroll
        for (int k = 0; k < 4; ++k) { int idx = t * 4 + k; if (idx < NB) lbase[idx] = run; run += v[k]; }
        if (t == 63) lbase[NB] = inc;  // == cn
    }
    __syncthreads();
    for (int i = t; i < NB; i += 512) {
        int c = cnt[i];
        gbase[i] = i * SLOT + atomicAdd(&gcur[i], c);  // reserve contiguous run
        cnt[i] = lbase[i];                             // rank cursors
    }
    __syncthreads();
    for (int e = e0 + t; e < e1; e += 512) {
        int s = src[e], d = dst[e];
        int bk = d >> 9;
        int r = atomicAdd(&cnt[bk], 1);     // LDS atomic
        sbuf[r] = (s << 9) | (d & (BN - 1));
        sbkt[r] = (unsigned char)bk;
    }
    __syncthreads();
    for (int i = t; i < cn; i += 512) {     // contiguous run write-out
        int bk = sbkt[i];
        staged[gbase[bk] + i - lbase[bk]] = sbuf[i];
    }
}

// ---------------- pass 2: per-bucket fine counting sort + node ranges + dis ----------------
__global__ __launch_bounds__(1024) void fine_kernel(const int* __restrict__ staged,
                                                    const int* __restrict__ gcur,
                                                    int2* __restrict__ offs2,
                                                    float* __restrict__ dis,
                                                    int* __restrict__ csr_src) {
    __shared__ int hist[BN];
    __shared__ int offs[BN];
    __shared__ int cur[BN];
    int t = threadIdx.x, j = blockIdx.x;
    int bb = j * SLOT;
    int be = bb + gcur[j];
    for (int i = t; i < BN; i += 1024) hist[i] = 0;
    __syncthreads();
    for (int e = bb + t; e < be; e += 1024) atomicAdd(&hist[staged[e] & (BN - 1)], 1);
    __syncthreads();
    if (t < 64) {  // wave0: exclusive scan of 512 counts, 8 per lane
        int v[8]; int s = 0;
#pragma unroll
        for (int k = 0; k < 8; ++k) { v[k] = hist[t * 8 + k]; s += v[k]; }
        int inc = s;
#pragma unroll
        for (int m = 1; m < 64; m <<= 1) {
            int u = __shfl_up(inc, m, 64);
            if (t >= m) inc += u;
        }
        int run = inc - s;
#pragma unroll
        for (int k = 0; k < 8; ++k) { offs[t * 8 + k] = run; run += v[k]; }
    }
    __syncthreads();
    for (int l = t; l < BN; l += 1024) {
        cur[l] = offs[l];
        int n = j * BN + l;
        if (n < NN) {
            int st = bb + offs[l];
            offs2[n] = make_int2(st, st + hist[l]);
            dis[n] = rsqrtf((float)hist[l] + 1.0f);
        }
    }
    __syncthreads();
    for (int e = bb + t; e < be; e += 1024) {
        int p = staged[e];
        int r = atomicAdd(&cur[p & (BN - 1)], 1);  // LDS atomic
        csr_src[bb + r] = p >> 9;
    }
}

// ---------------- matmul 1 (MFMA): ys1 = bf16(dis * (x @ W1)) ----------------
__global__ __launch_bounds__(256) void mm1_kernel(const float* __restrict__ x,
                                                  const float* __restrict__ W,
                                                  const float* __restrict__ dis,
                                                  unsigned short* __restrict__ y) {
    __shared__ unsigned short Wt[64][136];  // W^T bf16: [n][k], pad 8 shorts
    int t = threadIdx.x;
    for (int i = t; i < 128 * 64; i += 256) {
        int k = i >> 6, n = i & 63;
        Wt[n][k] = bf16_of(W[i]);
    }
    __syncthreads();
    int wave = t >> 6, lane = t & 63;
    int quad = lane >> 4, n16 = lane & 15;
    short8 bfr[4][4];  // [kstep][coltile]
#pragma unroll
    for (int s = 0; s < 4; ++s)
#pragma unroll
        for (int tt = 0; tt < 4; ++tt)
            bfr[s][tt] = *(const short8*)&Wt[tt * 16 + n16][s * 32 + quad * 8];
    int tile0 = (blockIdx.x * 4 + wave) * 4;
#pragma unroll 1
    for (int it = 0; it < 4; ++it) {
        int tile = tile0 + it;
        if (tile >= 6250) break;
        int m0 = tile * 16;
        const float* xp = x + (size_t)(m0 + n16) * 128 + quad * 8;
        floatx4 acc0 = {0,0,0,0}, acc1 = {0,0,0,0}, acc2 = {0,0,0,0}, acc3 = {0,0,0,0};
#pragma unroll
        for (int s = 0; s < 4; ++s) {
            float4 lo = *(const float4*)(xp + s * 32);
            float4 hi = *(const float4*)(xp + s * 32 + 4);
            short8 a;
            a[0] = (short)bf16_of(lo.x); a[1] = (short)bf16_of(lo.y);
            a[2] = (short)bf16_of(lo.z); a[3] = (short)bf16_of(lo.w);
            a[4] = (short)bf16_of(hi.x); a[5] = (short)bf16_of(hi.y);
            a[6] = (short)bf16_of(hi.z); a[7] = (short)bf16_of(hi.w);
            acc0 = __builtin_amdgcn_mfma_f32_16x16x32_bf16(a, bfr[s][0], acc0, 0, 0, 0);
            acc1 = __builtin_amdgcn_mfma_f32_16x16x32_bf16(a, bfr[s][1], acc1, 0, 0, 0);
            acc2 = __builtin_amdgcn_mfma_f32_16x16x32_bf16(a, bfr[s][2], acc2, 0, 0, 0);
            acc3 = __builtin_amdgcn_mfma_f32_16x16x32_bf16(a, bfr[s][3], acc3, 0, 0, 0);
        }
#pragma unroll
        for (int r = 0; r < 4; ++r) {
            int ro = m0 + quad * 4 + r;
            float sc = dis[ro];
            unsigned short* yp = y + (size_t)ro * 64 + n16;
            yp[0]  = bf16_of(acc0[r] * sc);
            yp[16] = bf16_of(acc1[r] * sc);
            yp[32] = bf16_of(acc2[r] * sc);
            yp[48] = bf16_of(acc3[r] * sc);
        }
    }
}

// ---------------- fused layer-1 aggregate + layer-2 matmul ----------------
__global__ __launch_bounds__(256) void agg64mm2_kernel(const uint4v* __restrict__ ys4,
                                                       const float* __restrict__ dis,
                                                       const int2* __restrict__ offs2,
                                                       const int* __restrict__ csr_src,
                                                       const float* __restrict__ b1,
                                                       const float* __restrict__ W2,
                                                       unsigned int* __restrict__ ys2) {
    __shared__ float w2s[64 * 32];      // 8KB fp32, [k][n] row-major
    __shared__ float hbuf[32 * 68];     // 8.5KB: 32 nodes x 64 k, stride 68 (bank-spread)
    int t = threadIdx.x;
    for (int i = t; i < 2048; i += 256) w2s[i] = W2[i];
    __syncthreads();
    int tid = blockIdx.x * 256 + t;
    int nd = tid >> 3, c = tid & 7;     // grid exact: nd < NN always
    int2 se = offs2[nd];
    int start = se.x, end = se.y;
    float acc[8] = {0, 0, 0, 0, 0, 0, 0, 0};
    acc8(acc, ys4[(size_t)nd * 8 + c]);  // self-loop term
    int i = start;
    int n8 = start + ((end - start) & ~7);
    for (; i < n8; i += 8) {
        int s0 = csr_src[i],     s1 = csr_src[i + 1], s2 = csr_src[i + 2], s3 = csr_src[i + 3];
        int s4 = csr_src[i + 4], s5 = csr_src[i + 5], s6 = csr_src[i + 6], s7 = csr_src[i + 7];
        uint4v r0 = ys4[(size_t)s0 * 8 + c];
        uint4v r1 = ys4[(size_t)s1 * 8 + c];
        uint4v r2 = ys4[(size_t)s2 * 8 + c];
        uint4v r3 = ys4[(size_t)s3 * 8 + c];
        uint4v r4 = ys4[(size_t)s4 * 8 + c];
        uint4v r5 = ys4[(size_t)s5 * 8 + c];
        uint4v r6 = ys4[(size_t)s6 * 8 + c];
        uint4v r7 = ys4[(size_t)s7 * 8 + c];
        acc8(acc, r0); acc8(acc, r1); acc8(acc, r2); acc8(acc, r3);
        acc8(acc, r4); acc8(acc, r5); acc8(acc, r6); acc8(acc, r7);
    }
    for (; i < end; ++i) acc8(acc, ys4[(size_t)csr_src[i] * 8 + c]);
    float ds = dis[nd];
    const float4 bv0 = *(const float4*)&b1[c * 8];
    const float4 bv1 = *(const float4*)&b1[c * 8 + 4];
    // h row (fp32, bias + relu) -> per-wave LDS exchange (same-wave, no barrier)
    float* hrow = &hbuf[(t >> 3) * 68];
    float4 h0, h1;
    h0.x = fmaxf(fmaf(ds, acc[0], bv0.x), 0.f);
    h0.y = fmaxf(fmaf(ds, acc[1], bv0.y), 0.f);
    h0.z = fmaxf(fmaf(ds, acc[2], bv0.z), 0.f);
    h0.w = fmaxf(fmaf(ds, acc[3], bv0.w), 0.f);
    h1.x = fmaxf(fmaf(ds, acc[4], bv1.x), 0.f);
    h1.y = fmaxf(fmaf(ds, acc[5], bv1.y), 0.f);
    h1.z = fmaxf(fmaf(ds, acc[6], bv1.z), 0.f);
    h1.w = fmaxf(fmaf(ds, acc[7], bv1.w), 0.f);
    *(float4*)&hrow[c * 8]     = h0;
    *(float4*)&hrow[c * 8 + 4] = h1;
    // z[c*4 .. c*4+3] = ds * sum_k h[k] * W2[k][n]
    float p0 = 0.f, p1 = 0.f, p2 = 0.f, p3 = 0.f;
#pragma unroll 8
    for (int k = 0; k < 64; ++k) {
        float hk = hrow[k];
        const float4 wr = *(const float4*)&w2s[k * 32 + c * 4];
        p0 = fmaf(hk, wr.x, p0);
        p1 = fmaf(hk, wr.y, p1);
        p2 = fmaf(hk, wr.z, p2);
        p3 = fmaf(hk, wr.w, p3);
    }
    p0 *= ds; p1 *= ds; p2 *= ds; p3 *= ds;
    unsigned int* zp = ys2 + (size_t)nd * 16 + c * 2;  // 32 bf16 = 16 uints per node
    zp[0] = pack2(p0, p1);
    zp[1] = pack2(p2, p3);
}

// ---------------- fused gather-aggregate, dim 32 bf16 -> z bf16, unroll 8 ----------------
__global__ __launch_bounds__(256) void agg32_kernel(const uint4v* __restrict__ ys4,
                                                    const float* __restrict__ dis,
                                                    const int2* __restrict__ offs2,
                                                    const int* __restrict__ csr_src,
                                                    const float* __restrict__ b,
                                                    uint4v* __restrict__ z4) {
    int tid = blockIdx.x * 256 + threadIdx.x;
    int nd = tid >> 2, c = tid & 3;
    if (nd >= NN) return;
    int2 se = offs2[nd];
    int start = se.x, end = se.y;
    float acc[8] = {0, 0, 0, 0, 0, 0, 0, 0};
    acc8(acc, ys4[(size_t)nd * 4 + c]);
    int i = start;
    int n8 = start + ((end - start) & ~7);
    for (; i < n8; i += 8) {
        int s0 = csr_src[i],     s1 = csr_src[i + 1], s2 = csr_src[i + 2], s3 = csr_src[i + 3];
        int s4 = csr_src[i + 4], s5 = csr_src[i + 5], s6 = csr_src[i + 6], s7 = csr_src[i + 7];
        uint4v r0 = ys4[(size_t)s0 * 4 + c];
        uint4v r1 = ys4[(size_t)s1 * 4 + c];
        uint4v r2 = ys4[(size_t)s2 * 4 + c];
        uint4v r3 = ys4[(size_t)s3 * 4 + c];
        uint4v r4 = ys4[(size_t)s4 * 4 + c];
        uint4v r5 = ys4[(size_t)s5 * 4 + c];
        uint4v r6 = ys4[(size_t)s6 * 4 + c];
        uint4v r7 = ys4[(size_t)s7 * 4 + c];
        acc8(acc, r0); acc8(acc, r1); acc8(acc, r2); acc8(acc, r3);
        acc8(acc, r4); acc8(acc, r5); acc8(acc, r6); acc8(acc, r7);
    }
    for (; i < end; ++i) acc8(acc, ys4[(size_t)csr_src[i] * 4 + c]);
    float ds = dis[nd];
    const float4 bv0 = *(const float4*)&b[c * 8];
    const float4 bv1 = *(const float4*)&b[c * 8 + 4];
    uint4v o;
    o[0] = pack2(fmaf(ds, acc[0], bv0.x), fmaf(ds, acc[1], bv0.y));
    o[1] = pack2(fmaf(ds, acc[2], bv0.z), fmaf(ds, acc[3], bv0.w));
    o[2] = pack2(fmaf(ds, acc[4], bv1.x), fmaf(ds, acc[5], bv1.y));
    o[3] = pack2(fmaf(ds, acc[6], bv1.z), fmaf(ds, acc[7], bv1.w));
    z4[(size_t)nd * 4 + c] = o;
}

// ---------------- decode: sigmoid(dot(z[src], z[dst])), 4 lanes/edge, bf16 z ---------
__global__ __launch_bounds__(256) void decode_kernel(const uint4v* __restrict__ z4,
                                                     const int* __restrict__ src,
                                                     const int* __restrict__ dst,
                                                     float* __restrict__ out) {
    int tid = blockIdx.x * 256 + threadIdx.x;
    int e = tid >> 2, k = tid & 3;
    if (e >= NE) return;
    int s = src[e], d = dst[e];
    uint4v ra = z4[(size_t)s * 4 + k];
    uint4v rb = z4[(size_t)d * 4 + k];
    float acc;
    acc  = lo_f(ra[0]) * lo_f(rb[0]) + hi_f(ra[0]) * hi_f(rb[0]);
    acc += lo_f(ra[1]) * lo_f(rb[1]) + hi_f(ra[1]) * hi_f(rb[1]);
    acc += lo_f(ra[2]) * lo_f(rb[2]) + hi_f(ra[2]) * hi_f(rb[2]);
    acc += lo_f(ra[3]) * lo_f(rb[3]) + hi_f(ra[3]) * hi_f(rb[3]);
#pragma unroll
    for (int m = 2; m >= 1; m >>= 1) acc += __shfl_xor(acc, m, 4);
    if (k == 0) out[e] = 1.0f / (1.0f + expf(-acc));
}

// ---------------- launcher ----------------
extern "C" void kernel_launch(void* const* d_in, const int* in_sizes, int n_in,
                              void* d_out, int out_size, void* d_ws, size_t ws_size,
                              hipStream_t stream) {
    const float* emb = (const float*)d_in[0];
    const float* W1  = (const float*)d_in[1];
    const float* b1  = (const float*)d_in[2];
    const float* W2  = (const float*)d_in[3];
    const float* b2  = (const float*)d_in[4];
    const int*   ei  = (const int*)d_in[5];
    const int* src = ei;
    const int* dst = ei + NE;
    float* out = (float*)d_out;

    // workspace layout
    char* w = (char*)d_ws;
    int2*  offs2       = (int2*)w;          w += (size_t)NPAD * 8;         // 800KB
    float* dis         = (float*)w;         w += (size_t)NPAD * 4;
    int*   gcur        = (int*)w;           w += 1024;                     // NB cursors
    int*   csr_src     = (int*)w;           w += (size_t)NB * SLOT * 4;    // 14.5MB
    int*   staged      = (int*)w;           w += (size_t)NB * SLOT * 4;    // 14.5MB packed
    unsigned short* ysbuf = (unsigned short*)w; w += (size_t)NN * 64 * 2;  // 12.8MB bf16
    unsigned short* ys2 = (unsigned short*)w;                              // 6.4MB bf16
    unsigned short* ys1 = ysbuf;
    unsigned short* z   = ysbuf;            // overlays dead ys1 after agg64mm2

    // CSR build — 2 kernels: slab-reserving scatter + fine counting sort
    hipMemsetAsync(gcur, 0, NB * 4, stream);
    scatter_kernel<<<NBLK, 512, 0, stream>>>(src, dst, gcur, staged);
    fine_kernel<<<NB, 1024, 0, stream>>>(staged, gcur, offs2, dis, csr_src);

    // layer 1 matmul
    mm1_kernel<<<391, 256, 0, stream>>>(emb, W1, dis, ys1);
    // fused: layer-1 aggregate (+bias,relu) + layer-2 matmul -> ys2
    agg64mm2_kernel<<<(NN * 8) / 256, 256, 0, stream>>>((const uint4v*)ys1, dis, offs2, csr_src,
                                                        b1, W2, (unsigned int*)ys2);
    // layer-2 aggregate -> z (overlays dead ys1)
    agg32_kernel<<<(NN * 4 + 255) / 256, 256, 0, stream>>>((const uint4v*)ys2, dis, offs2, csr_src, b2, (uint4v*)z);

    // decode
    decode_kernel<<<(NE * 4) / 256, 256, 0, stream>>>((const uint4v*)z, src, dst, out);
}